// Round 5
// baseline (400.120 us; speedup 1.0000x reference)
//
#include <hip/hip_runtime.h>
#include <hip/hip_bf16.h>
#include <cstddef>
#include <cstdint>

// Problem constants
#define B_DIM 4096
#define D_DIM 2048
#define S_DIM 2048
#define KNOTS 20
#define T_MAX 5.0f

typedef unsigned short ushort_t;
typedef __attribute__((ext_vector_type(8))) short short8_t;    // 8 bf16 (4 VGPR)
typedef __attribute__((ext_vector_type(4))) float f32x4;
typedef __attribute__((ext_vector_type(8))) unsigned short ushort8_t;
typedef __attribute__((ext_vector_type(4))) unsigned short ushort4_t;

// ---- bf16 helpers ----
__device__ __forceinline__ ushort_t f2bf(float f) {
    unsigned u = __float_as_uint(f);
    u += 0x7FFFu + ((u >> 16) & 1u);     // round-to-nearest-even
    return (ushort_t)(u >> 16);
}
__device__ __forceinline__ float bf2f(ushort_t h) {
    return __uint_as_float(((unsigned)h) << 16);
}

// ---- async global->LDS 16B ----
__device__ __forceinline__ void gload16(const void* g, void* l) {
    __builtin_amdgcn_global_load_lds(
        (const __attribute__((address_space(1))) unsigned int*)g,
        (__attribute__((address_space(3))) unsigned int*)l, 16, 0, 0);
}

// ===========================================================================
// kprep: ONE kernel for all preprocessing (saves ~4 graph nodes @ ~14us each)
//   blocks [0, 4096)   : E [B][D] fp32 -> Eh, El bf16 hi/lo   (kconvE)
//   blocks [4096, 4128): A strip [2048][64] -> col norms (in-block, no
//                        atomics/memset) -> Aht, Alt [S][D] normalized bf16
//   block 0 thread 0   : zeroes out[0] (runs before kfinal's atomics)
// ===========================================================================
__global__ __launch_bounds__(256) void kprep(const float* __restrict__ E,
                                             const float* __restrict__ A,
                                             ushort_t* __restrict__ Eh,
                                             ushort_t* __restrict__ El,
                                             ushort_t* __restrict__ Aht,
                                             ushort_t* __restrict__ Alt,
                                             float* __restrict__ out) {
    const int bx = blockIdx.x;
    const int tid = threadIdx.x;
    if (bx == 0 && tid == 0) out[0] = 0.f;

    if (bx < 4096) {
        // ---- convE ----
        const size_t i = ((size_t)bx * 256 + tid) * 8;
        float4 v0 = *(const float4*)&E[i];
        float4 v1 = *(const float4*)&E[i + 4];
        float f[8] = {v0.x, v0.y, v0.z, v0.w, v1.x, v1.y, v1.z, v1.w};
        ushort8_t h, l;
#pragma unroll
        for (int j = 0; j < 8; ++j) {
            ushort_t hb = f2bf(f[j]);
            h[j] = hb;
            l[j] = f2bf(f[j] - bf2f(hb));
        }
        *(ushort8_t*)&Eh[i] = h;
        *(ushort8_t*)&El[i] = l;
        return;
    }

    // ---- norm + convA for s-columns [s0, s0+64) ----
    __shared__ float T[64][69];
    __shared__ float nr[4][64];
    __shared__ float invn_s[64];
    const int s0 = (bx - 4096) * 64;
    const int sc = tid & 63, dg = tid >> 6;

    // phase 1: column sum-of-squares over full D (coalesced 256B rows)
    float nacc = 0.f;
    for (int d = dg; d < D_DIM; d += 4) {
        float v = A[(size_t)d * S_DIM + s0 + sc];
        nacc = fmaf(v, v, nacc);
    }
    nr[dg][sc] = nacc;
    __syncthreads();
    if (dg == 0)
        invn_s[sc] = rsqrtf(nr[0][sc] + nr[1][sc] + nr[2][sc] + nr[3][sc]);
    __syncthreads();

    // phase 2: 64x64 tile transpose + normalize + hi/lo split (L2-hot re-read)
    const int dl = tid >> 2, c4 = tid & 3;
    for (int d0 = 0; d0 < D_DIM; d0 += 64) {
#pragma unroll
        for (int q = 0; q < 4; ++q) {
            int scc = c4 * 16 + q * 4;
            float4 v = *(const float4*)&A[(size_t)(d0 + dl) * S_DIM + s0 + scc];
            T[dl][scc + 0] = v.x; T[dl][scc + 1] = v.y;
            T[dl][scc + 2] = v.z; T[dl][scc + 3] = v.w;
        }
        __syncthreads();
#pragma unroll
        for (int p = 0; p < 4; ++p) {
            int sl = p * 16 + (tid >> 4);
            float invn = invn_s[sl];
            int dof = (tid & 15) * 4;
            ushort4_t h, l;
#pragma unroll
            for (int i = 0; i < 4; ++i) {
                float x = T[dof + i][sl] * invn;
                ushort_t hb = f2bf(x);
                h[i] = hb;
                l[i] = f2bf(x - bf2f(hb));
            }
            *(ushort4_t*)&Aht[(size_t)(s0 + sl) * D_DIM + d0 + dof] = h;
            *(ushort4_t*)&Alt[(size_t)(s0 + sl) * D_DIM + d0 + dof] = l;
        }
        __syncthreads();
    }
}

// ===========================================================================
// kmain: split-bf16 MFMA GEMM + CF epilogue. 2-phase pipelined, LDS dbuf,
// XOR-swizzled LDS (conflict-free b128 frag reads), XCD-swizzled blocks.
// Per K-step: ds_read(cur) -> STAGE(next) -> MFMA -> barrier.
// LDS swizzle: physical 16B chunk p of row r holds logical k-chunk
// q = p ^ ((r>>1)&3)  => bank-span = 16(r&1)+4p covers all 8 spans per
// 8 consecutive lanes. Staging stays LINEAR (gload_lds requirement);
// the global SOURCE address is pre-swizzled instead (rule #21).
// ===========================================================================
__global__ __launch_bounds__(256, 2) void kmain(const ushort_t* __restrict__ Eh,
                                                const ushort_t* __restrict__ El,
                                                const ushort_t* __restrict__ Aht,
                                                const ushort_t* __restrict__ Alt,
                                                float* __restrict__ partials) {
    __shared__ __align__(16) char smem[65536];   // 2 x 32KB dbuf; cf aliases
    float* cf = (float*)smem;

    const int tid = threadIdx.x;
    const int lane = tid & 63, wid = tid >> 6;
    const int wm = (wid & 1) * 64, wn = (wid >> 1) * 64;

    // T1: bijective XCD-aware remap (512 blocks, 512%8==0)
    const int lin = blockIdx.y * gridDim.x + blockIdx.x;
    const int wg = (lin & 7) * 64 + (lin >> 3);
    const int sblk = wg & 15, bchunk = wg >> 4;
    const int s0 = sblk * 128, b0 = bchunk * 128;

    f32x4 acc[4][4];
#pragma unroll
    for (int mt = 0; mt < 4; ++mt)
#pragma unroll
        for (int nt = 0; nt < 4; ++nt)
            acc[mt][nt] = (f32x4){0.f, 0.f, 0.f, 0.f};

    const int r_ld = tid >> 2;                       // staging row 0..63
    const int c_ld = tid & 3;                        // physical 16B chunk
    const int lds_lin = tid * 8;                     // linear LDS dest (ushort)
    const int kq_src = (c_ld ^ ((r_ld >> 1) & 3)) * 8;   // swizzled global k-chunk
    // frag read: same XOR on the read side
    const int rswz = ((lane & 15) >> 1) & 3;
    const int kphys = ((lane >> 4) ^ rswz) * 8;      // physical k-offset (ushort)

#define STAGE(P, KT)                                                           \
    {                                                                          \
        ushort_t* base_ = (ushort_t*)smem + (P) * 16384;                       \
        _Pragma("unroll")                                                      \
        for (int st = 0; st < 2; ++st) {                                       \
            const int r_ = st * 64 + r_ld;                                     \
            const size_t eoff_ = (size_t)(b0 + r_) * D_DIM + (KT) + kq_src;    \
            const size_t aoff_ = (size_t)(s0 + r_) * D_DIM + (KT) + kq_src;    \
            const int ldo_ = st * 2048 + lds_lin;                              \
            gload16(Eh + eoff_, base_ + ldo_);                                 \
            gload16(El + eoff_, base_ + 4096 + ldo_);                          \
            gload16(Aht + aoff_, base_ + 8192 + ldo_);                         \
            gload16(Alt + aoff_, base_ + 12288 + ldo_);                        \
        }                                                                      \
    }

    STAGE(0, 0);
    __syncthreads();                 // buf0 ready

#pragma unroll 2
    for (int it = 0; it < 64; ++it) {
        const int cur = it & 1;
        ushort_t* base = (ushort_t*)smem + cur * 16384;

        // 1) ds_read frags from buf[cur] (conflict-free via swizzle)
        short8_t ah[4], al[4], bh[4], bl[4];
#pragma unroll
        for (int mt = 0; mt < 4; ++mt) {
            int row = wm + mt * 16 + (lane & 15);
            ah[mt] = *(const short8_t*)&base[row * 32 + kphys];
            al[mt] = *(const short8_t*)&base[4096 + row * 32 + kphys];
        }
#pragma unroll
        for (int nt = 0; nt < 4; ++nt) {
            int row = wn + nt * 16 + (lane & 15);
            bh[nt] = *(const short8_t*)&base[8192 + row * 32 + kphys];
            bl[nt] = *(const short8_t*)&base[12288 + row * 32 + kphys];
        }
        __builtin_amdgcn_sched_barrier(0);

        // 2) issue next tile's staging into buf[cur^1]; loads stay in flight
        //    under the MFMA block below (drained at this iter's barrier).
        if (it + 1 < 64) STAGE(cur ^ 1, (it + 1) * 32);
        __builtin_amdgcn_sched_barrier(0);

        // 3) register-only MFMA block
#pragma unroll
        for (int mt = 0; mt < 4; ++mt)
#pragma unroll
            for (int nt = 0; nt < 4; ++nt) {
                acc[mt][nt] = __builtin_amdgcn_mfma_f32_16x16x32_bf16(ah[mt], bh[nt], acc[mt][nt], 0, 0, 0);
                acc[mt][nt] = __builtin_amdgcn_mfma_f32_16x16x32_bf16(ah[mt], bl[nt], acc[mt][nt], 0, 0, 0);
                acc[mt][nt] = __builtin_amdgcn_mfma_f32_16x16x32_bf16(al[mt], bh[nt], acc[mt][nt], 0, 0, 0);
            }
        __syncthreads();             // one barrier per K-step
    }
#undef STAGE

    // ---- CF epilogue on acc registers ----
    // C layout (16x16x32): col = lane&15, row = (lane>>4)*4 + reg.
    const float DT = T_MAX / (float)(KNOTS - 1);

#pragma unroll
    for (int nt = 0; nt < 4; ++nt) {
        float re[KNOTS - 1], im[KNOTS - 1];
#pragma unroll
        for (int k = 0; k < KNOTS - 1; ++k) { re[k] = 0.f; im[k] = 0.f; }
#pragma unroll
        for (int mt = 0; mt < 4; ++mt) {
            f32x4 v = acc[mt][nt];
#pragma unroll
            for (int r = 0; r < 4; ++r) {
                float p = v[r];
                float sn, cs;
                __sincosf(p * DT, &sn, &cs);
                float c = cs, s = sn;
                re[0] += c; im[0] += s;
#pragma unroll
                for (int k = 1; k < KNOTS - 1; ++k) {
                    float cn = fmaf(c, cs, -s * sn);
                    s = fmaf(s, cs, c * sn);
                    c = cn;
                    re[k] += c; im[k] += s;
                }
            }
        }
#pragma unroll
        for (int k = 0; k < KNOTS - 1; ++k) {
            re[k] += __shfl_xor(re[k], 16);
            re[k] += __shfl_xor(re[k], 32);
            im[k] += __shfl_xor(im[k], 16);
            im[k] += __shfl_xor(im[k], 32);
        }
        if (lane < 16) {
            const int sig = nt * 16 + lane;
            float* dst = &cf[(size_t)((((wid & 1) * 2 + (wid >> 1)) * 64 + sig)) * 38];
#pragma unroll
            for (int k = 0; k < KNOTS - 1; ++k) {
                dst[2 * k]     = re[k];
                dst[2 * k + 1] = im[k];
            }
        }
    }
    __syncthreads();

    // combine the two m-parity waves; coalesced partials write
#pragma unroll
    for (int i = 0; i < KNOTS - 1; ++i) {
        const int kc2 = i * 2 + (tid >> 7);   // 0..37
        const int sl = tid & 127;
        const int g = sl >> 6, si = sl & 63;
        float v = cf[(size_t)(((0 * 2 + g) * 64 + si)) * 38 + kc2]
                + cf[(size_t)(((1 * 2 + g) * 64 + si)) * 38 + kc2];
        const int k = kc2 >> 1, c = kc2 & 1;
        partials[((size_t)(bchunk * (KNOTS - 1) + k) * 2 + c) * S_DIM + s0 + sl] = v;
    }
}

// ===========================================================================
// kfinal: sum chunk partials, weighted err, reduce, atomicAdd scalar.
// ===========================================================================
template <int NCH>
__global__ __launch_bounds__(256) void kfinal(const float* __restrict__ partials,
                                              const float* __restrict__ phi,
                                              const float* __restrict__ wts,
                                              float* __restrict__ out) {
    const int idx = blockIdx.x * 256 + threadIdx.x;
    const int kk = idx >> 11;
    const int s = idx & (S_DIM - 1);
    const float invB = 1.0f / (float)B_DIM;

    float re = 0.f, im = 0.f;
    for (int ch = 0; ch < NCH; ++ch) {
        re += partials[(size_t)((ch * (KNOTS - 1) + kk) * 2 + 0) * S_DIM + s];
        im += partials[(size_t)((ch * (KNOTS - 1) + kk) * 2 + 1) * S_DIM + s];
    }
    re = re * invB - phi[kk + 1];
    im *= invB;
    float local = wts[kk + 1] * fmaf(re, re, im * im);

    __shared__ float sred[256];
    sred[threadIdx.x] = local;
    __syncthreads();
    for (int off = 128; off > 0; off >>= 1) {
        if (threadIdx.x < off) sred[threadIdx.x] += sred[threadIdx.x + off];
        __syncthreads();
    }
    if (threadIdx.x == 0) {
        const float scale = (float)D_DIM / (float)S_DIM;
        atomicAdd(out, sred[0] * scale);
    }
}

// ===========================================================================
// Fallback fp32 path (validated round 2) for small ws_size
// ===========================================================================
#define BM 64
#define BN 64
#define BK 16
#define BTILES 2
#define NCHUNK_F (B_DIM / (BM * BTILES))

__global__ __launch_bounds__(256) void knorm(const float* __restrict__ A,
                                             float* __restrict__ norm2) {
    const int tid = threadIdx.x;
    const int j = tid & 63;
    const int g = tid >> 6;
    const int s = blockIdx.x * 64 + j;
    const int d0 = blockIdx.y * 256 + g * 64;
    float acc = 0.f;
#pragma unroll 8
    for (int i = 0; i < 64; ++i) {
        float v = A[(size_t)(d0 + i) * S_DIM + s];
        acc = fmaf(v, v, acc);
    }
    __shared__ float red[256];
    red[tid] = acc;
    __syncthreads();
    if (tid < 64) {
        float v = red[tid] + red[tid + 64] + red[tid + 128] + red[tid + 192];
        atomicAdd(&norm2[s], v);
    }
}

template <bool ATOMIC>
__global__ __launch_bounds__(256, 2) void kfused_f32(const float* __restrict__ E,
                                                     const float* __restrict__ A,
                                                     const float* __restrict__ norm2,
                                                     float* __restrict__ partials) {
    const int sblk = blockIdx.x;
    const int bchunk = blockIdx.y;
    const int s0 = sblk * BN;
    const int tid = threadIdx.x;
    const int tx = tid & 15, ty = tid >> 4;
    const int j = tid & 63, g = tid >> 6;

    __shared__ float As[BK][BM + 4];
    __shared__ float Bs[BK][BN + 4];
    __shared__ float Pj[BM][BN + 4];

    const float invn = rsqrtf(norm2[s0 + j]);
    const float DTSTEP = T_MAX / (float)(KNOTS - 1);

    float accRe[KNOTS - 1], accIm[KNOTS - 1];
#pragma unroll
    for (int k = 0; k < KNOTS - 1; ++k) { accRe[k] = 0.f; accIm[k] = 0.f; }

    const int lrow = tid >> 2, lq = tid & 3;
    const int brow = tid >> 4, bq = tid & 15;

    for (int bt = 0; bt < BTILES; ++bt) {
        const int b0 = (bchunk * BTILES + bt) * BM;
        float acc[4][4];
#pragma unroll
        for (int i = 0; i < 4; ++i)
#pragma unroll
            for (int jj = 0; jj < 4; ++jj) acc[i][jj] = 0.f;

        float4 ev = *(const float4*)&E[(size_t)(b0 + lrow) * D_DIM + 0 + lq * 4];
        float4 av = *(const float4*)&A[(size_t)(0 + brow) * S_DIM + s0 + bq * 4];

        for (int kt = 0; kt < D_DIM; kt += BK) {
            __syncthreads();
            As[lq * 4 + 0][lrow] = ev.x;
            As[lq * 4 + 1][lrow] = ev.y;
            As[lq * 4 + 2][lrow] = ev.z;
            As[lq * 4 + 3][lrow] = ev.w;
            *(float4*)&Bs[brow][bq * 4] = av;
            __syncthreads();
            if (kt + BK < D_DIM) {
                ev = *(const float4*)&E[(size_t)(b0 + lrow) * D_DIM + (kt + BK) + lq * 4];
                av = *(const float4*)&A[(size_t)(kt + BK + brow) * S_DIM + s0 + bq * 4];
            }
#pragma unroll
            for (int kk = 0; kk < BK; ++kk) {
                float4 a = *(const float4*)&As[kk][ty * 4];
                float4 b = *(const float4*)&Bs[kk][tx * 4];
                acc[0][0] = fmaf(a.x, b.x, acc[0][0]);
                acc[0][1] = fmaf(a.x, b.y, acc[0][1]);
                acc[0][2] = fmaf(a.x, b.z, acc[0][2]);
                acc[0][3] = fmaf(a.x, b.w, acc[0][3]);
                acc[1][0] = fmaf(a.y, b.x, acc[1][0]);
                acc[1][1] = fmaf(a.y, b.y, acc[1][1]);
                acc[1][2] = fmaf(a.y, b.z, acc[1][2]);
                acc[1][3] = fmaf(a.y, b.w, acc[1][3]);
                acc[2][0] = fmaf(a.z, b.x, acc[2][0]);
                acc[2][1] = fmaf(a.z, b.y, acc[2][1]);
                acc[2][2] = fmaf(a.z, b.z, acc[2][2]);
                acc[2][3] = fmaf(a.z, b.w, acc[2][3]);
                acc[3][0] = fmaf(a.w, b.x, acc[3][0]);
                acc[3][1] = fmaf(a.w, b.y, acc[3][1]);
                acc[3][2] = fmaf(a.w, b.z, acc[3][2]);
                acc[3][3] = fmaf(a.w, b.w, acc[3][3]);
            }
        }
        __syncthreads();
#pragma unroll
        for (int i = 0; i < 4; ++i)
            *(float4*)&Pj[ty * 4 + i][tx * 4] =
                make_float4(acc[i][0], acc[i][1], acc[i][2], acc[i][3]);
        __syncthreads();

#pragma unroll 2
        for (int bl = g * 16; bl < g * 16 + 16; ++bl) {
            float p = Pj[bl][j] * invn;
            float sn, cs;
            __sincosf(p * DTSTEP, &sn, &cs);
            float c = cs, s = sn;
            accRe[0] += c; accIm[0] += s;
#pragma unroll
            for (int kk = 1; kk < KNOTS - 1; ++kk) {
                float cn = fmaf(c, cs, -s * sn);
                s = fmaf(s, cs, c * sn);
                c = cn;
                accRe[kk] += c; accIm[kk] += s;
            }
        }
    }

    __syncthreads();
    float* red = &Pj[0][0];
    if (g == 0) {
#pragma unroll
        for (int kk = 0; kk < KNOTS - 1; ++kk) {
            red[(kk * 2 + 0) * 64 + j] = accRe[kk];
            red[(kk * 2 + 1) * 64 + j] = accIm[kk];
        }
    }
    __syncthreads();
    for (int gg = 1; gg < 4; ++gg) {
        if (g == gg) {
#pragma unroll
            for (int kk = 0; kk < KNOTS - 1; ++kk) {
                red[(kk * 2 + 0) * 64 + j] += accRe[kk];
                red[(kk * 2 + 1) * 64 + j] += accIm[kk];
            }
        }
        __syncthreads();
    }

    if (tid < 64) {
        for (int kk = 0; kk < KNOTS - 1; ++kk) {
            for (int c = 0; c < 2; ++c) {
                const int row = ATOMIC ? kk : (bchunk * (KNOTS - 1) + kk);
                float* dst = &partials[(size_t)(row * 2 + c) * S_DIM + s0 + tid];
                const float v = red[(kk * 2 + c) * 64 + tid];
                if (ATOMIC) atomicAdd(dst, v);
                else        *dst = v;
            }
        }
    }
}

// ===========================================================================
extern "C" void kernel_launch(void* const* d_in, const int* in_sizes, int n_in,
                              void* d_out, int out_size, void* d_ws, size_t ws_size,
                              hipStream_t stream) {
    const float* E   = (const float*)d_in[0];
    const float* A   = (const float*)d_in[1];
    const float* phi = (const float*)d_in[3];
    const float* wts = (const float*)d_in[4];
    float* out = (float*)d_out;

    float* ws_f = (float*)d_ws;

    const size_t part_elems = (size_t)32 * (KNOTS - 1) * 2 * S_DIM;  // 2,490,368
    // Big path layout: partials | Eh | El | Aht | Alt
    float* partials = ws_f;
    ushort_t* Ehp  = (ushort_t*)(ws_f + part_elems);
    ushort_t* Elp  = Ehp + (size_t)B_DIM * D_DIM;
    ushort_t* Ahtp = Elp + (size_t)B_DIM * D_DIM;
    ushort_t* Altp = Ahtp + (size_t)S_DIM * D_DIM;

    const size_t need_bytes = part_elems * sizeof(float)
                            + (2 * (size_t)B_DIM * D_DIM + 2 * (size_t)S_DIM * D_DIM) * sizeof(ushort_t);

    if (ws_size >= need_bytes) {
        // 3 graph nodes total
        kprep<<<dim3(4096 + S_DIM / 64), 256, 0, stream>>>(E, A, Ehp, Elp, Ahtp, Altp, out);
        kmain<<<dim3(S_DIM / 128, B_DIM / 128), 256, 0, stream>>>(Ehp, Elp, Ahtp, Altp, partials);
        kfinal<32><<<dim3((KNOTS - 1) * S_DIM / 256), 256, 0, stream>>>(partials, phi, wts, out);
    } else {
        // fallback fp32 path (norm2 | partials layout)
        float* norm2 = ws_f;
        float* partials_f = ws_f + S_DIM;
        hipMemsetAsync(norm2, 0, S_DIM * sizeof(float), stream);
        hipMemsetAsync(out, 0, sizeof(float), stream);
        knorm<<<dim3(S_DIM / 64, D_DIM / 256), 256, 0, stream>>>(A, norm2);
        if (ws_size >= (S_DIM + part_elems) * sizeof(float)) {
            kfused_f32<false><<<dim3(S_DIM / BN, NCHUNK_F), 256, 0, stream>>>(E, A, norm2, partials_f);
            kfinal<NCHUNK_F><<<dim3((KNOTS - 1) * S_DIM / 256), 256, 0, stream>>>(partials_f, phi, wts, out);
        } else {
            hipMemsetAsync(partials_f, 0, (size_t)(KNOTS - 1) * 2 * S_DIM * sizeof(float), stream);
            kfused_f32<true><<<dim3(S_DIM / BN, NCHUNK_F), 256, 0, stream>>>(E, A, norm2, partials_f);
            kfinal<1><<<dim3((KNOTS - 1) * S_DIM / 256), 256, 0, stream>>>(partials_f, phi, wts, out);
        }
    }
}

// Round 6
// 235.298 us; speedup vs baseline: 1.7005x; 1.7005x over previous
//
#include <hip/hip_runtime.h>
#include <hip/hip_bf16.h>
#include <cstddef>
#include <cstdint>

// Problem constants
#define B_DIM 4096
#define D_DIM 2048
#define S_DIM 2048
#define KNOTS 20
#define T_MAX 5.0f

typedef unsigned short ushort_t;
typedef __attribute__((ext_vector_type(8))) short short8_t;    // 8 bf16 (4 VGPR)
typedef __attribute__((ext_vector_type(4))) float f32x4;
typedef __attribute__((ext_vector_type(8))) unsigned short ushort8_t;
typedef __attribute__((ext_vector_type(4))) unsigned short ushort4_t;

// ---- bf16 helpers ----
__device__ __forceinline__ ushort_t f2bf(float f) {
    unsigned u = __float_as_uint(f);
    u += 0x7FFFu + ((u >> 16) & 1u);     // round-to-nearest-even
    return (ushort_t)(u >> 16);
}
__device__ __forceinline__ float bf2f(ushort_t h) {
    return __uint_as_float(((unsigned)h) << 16);
}

// ---- async global->LDS 16B ----
__device__ __forceinline__ void gload16(const void* g, void* l) {
    __builtin_amdgcn_global_load_lds(
        (const __attribute__((address_space(1))) unsigned int*)g,
        (__attribute__((address_space(3))) unsigned int*)l, 16, 0, 0);
}

// ===========================================================================
// kconv: ALL preprocessing, fully parallel (no inter-block dependencies).
//   blocks [0, 4096)     : E [B][D] fp32 -> Eh, El bf16 hi/lo
//   blocks [4096, 5120)  : A 64x64 tile -> UNNORMALIZED Aht, Alt [S][D] bf16
//                          hi/lo + per-tile column sumsq -> norm_part[dblk][s]
//                          (normalization is applied in kmain's epilogue:
//                           proj*invn == (E @ A_raw)*invn, commutes with dot)
//   block 0 thread 0     : zeroes out[0] (kfinal atomics run later in stream)
// ===========================================================================
__global__ __launch_bounds__(256) void kconv(const float* __restrict__ E,
                                             const float* __restrict__ A,
                                             ushort_t* __restrict__ Eh,
                                             ushort_t* __restrict__ El,
                                             ushort_t* __restrict__ Aht,
                                             ushort_t* __restrict__ Alt,
                                             float* __restrict__ norm_part,
                                             float* __restrict__ out) {
    const int bx = blockIdx.x;
    const int tid = threadIdx.x;
    if (bx == 0 && tid == 0) out[0] = 0.f;

    if (bx < 4096) {
        // ---- E hi/lo split ----
        const size_t i = ((size_t)bx * 256 + tid) * 8;
        float4 v0 = *(const float4*)&E[i];
        float4 v1 = *(const float4*)&E[i + 4];
        float f[8] = {v0.x, v0.y, v0.z, v0.w, v1.x, v1.y, v1.z, v1.w};
        ushort8_t h, l;
#pragma unroll
        for (int j = 0; j < 8; ++j) {
            ushort_t hb = f2bf(f[j]);
            h[j] = hb;
            l[j] = f2bf(f[j] - bf2f(hb));
        }
        *(ushort8_t*)&Eh[i] = h;
        *(ushort8_t*)&El[i] = l;
        return;
    }

    // ---- A tile: transpose + split + partial column sumsq ----
    __shared__ float T[64][69];
    __shared__ float nr[4][64];
    const int idx = bx - 4096;                 // 0..1023
    const int dblk = idx >> 5, sblk = idx & 31;
    const int d0 = dblk * 64, s0 = sblk * 64;

    const int dl = tid >> 2, c4 = tid & 3;
#pragma unroll
    for (int q = 0; q < 4; ++q) {
        int sc = c4 * 16 + q * 4;
        float4 v = *(const float4*)&A[(size_t)(d0 + dl) * S_DIM + s0 + sc];
        T[dl][sc + 0] = v.x; T[dl][sc + 1] = v.y;
        T[dl][sc + 2] = v.z; T[dl][sc + 3] = v.w;
    }
    __syncthreads();

    // per-column sumsq over this tile's 64 d-rows (4 groups x 16 rows)
    {
        const int c = tid & 63, g = tid >> 6;
        float acc = 0.f;
#pragma unroll
        for (int i = 0; i < 16; ++i) {
            float v = T[g * 16 + i][c];
            acc = fmaf(v, v, acc);
        }
        nr[g][c] = acc;
    }
    __syncthreads();
    if (tid < 64)
        norm_part[(size_t)dblk * S_DIM + s0 + tid] =
            nr[0][tid] + nr[1][tid] + nr[2][tid] + nr[3][tid];

    // transpose + hi/lo split (NO normalization here)
#pragma unroll
    for (int p = 0; p < 4; ++p) {
        int sl = p * 16 + (tid >> 4);
        int dof = (tid & 15) * 4;
        ushort4_t h, l;
#pragma unroll
        for (int i = 0; i < 4; ++i) {
            float x = T[dof + i][sl];
            ushort_t hb = f2bf(x);
            h[i] = hb;
            l[i] = f2bf(x - bf2f(hb));
        }
        *(ushort4_t*)&Aht[(size_t)(s0 + sl) * D_DIM + d0 + dof] = h;
        *(ushort4_t*)&Alt[(size_t)(s0 + sl) * D_DIM + d0 + dof] = l;
    }
}

// ===========================================================================
// kmain: split-bf16 MFMA GEMM + CF epilogue. 2-phase pipelined, LDS dbuf,
// XOR-swizzled LDS (conflict-free b128 frag reads), XCD-swizzled blocks.
// Per K-step: ds_read(cur) -> STAGE(next) -> MFMA -> barrier.
// Normalization (invn per s-column) applied in the epilogue before sincos.
// ===========================================================================
__global__ __launch_bounds__(256, 2) void kmain(const ushort_t* __restrict__ Eh,
                                                const ushort_t* __restrict__ El,
                                                const ushort_t* __restrict__ Aht,
                                                const ushort_t* __restrict__ Alt,
                                                const float* __restrict__ norm_part,
                                                float* __restrict__ partials) {
    __shared__ __align__(16) char smem[65536];   // 2 x 32KB dbuf; cf aliases
    __shared__ float invn_lds[128];
    float* cf = (float*)smem;

    const int tid = threadIdx.x;
    const int lane = tid & 63, wid = tid >> 6;
    const int wm = (wid & 1) * 64, wn = (wid >> 1) * 64;

    // T1: bijective XCD-aware remap (512 blocks, 512%8==0)
    const int lin = blockIdx.y * gridDim.x + blockIdx.x;
    const int wg = (lin & 7) * 64 + (lin >> 3);
    const int sblk = wg & 15, bchunk = wg >> 4;
    const int s0 = sblk * 128, b0 = bchunk * 128;

    f32x4 acc[4][4];
#pragma unroll
    for (int mt = 0; mt < 4; ++mt)
#pragma unroll
        for (int nt = 0; nt < 4; ++nt)
            acc[mt][nt] = (f32x4){0.f, 0.f, 0.f, 0.f};

    const int r_ld = tid >> 2;                       // staging row 0..63
    const int c_ld = tid & 3;                        // physical 16B chunk
    const int lds_lin = tid * 8;                     // linear LDS dest (ushort)
    const int kq_src = (c_ld ^ ((r_ld >> 1) & 3)) * 8;   // swizzled global k-chunk
    const int rswz = ((lane & 15) >> 1) & 3;
    const int kphys = ((lane >> 4) ^ rswz) * 8;      // physical k-offset (ushort)

#define STAGE(P, KT)                                                           \
    {                                                                          \
        ushort_t* base_ = (ushort_t*)smem + (P) * 16384;                       \
        _Pragma("unroll")                                                      \
        for (int st = 0; st < 2; ++st) {                                       \
            const int r_ = st * 64 + r_ld;                                     \
            const size_t eoff_ = (size_t)(b0 + r_) * D_DIM + (KT) + kq_src;    \
            const size_t aoff_ = (size_t)(s0 + r_) * D_DIM + (KT) + kq_src;    \
            const int ldo_ = st * 2048 + lds_lin;                              \
            gload16(Eh + eoff_, base_ + ldo_);                                 \
            gload16(El + eoff_, base_ + 4096 + ldo_);                          \
            gload16(Aht + aoff_, base_ + 8192 + ldo_);                         \
            gload16(Alt + aoff_, base_ + 12288 + ldo_);                        \
        }                                                                      \
    }

    STAGE(0, 0);
    // invn for this block's 128 s-columns (L2-hot; hides under STAGE(0))
    if (tid < 128) {
        float n2 = 0.f;
#pragma unroll 8
        for (int d = 0; d < 32; ++d)
            n2 += norm_part[(size_t)d * S_DIM + s0 + tid];
        invn_lds[tid] = rsqrtf(n2);
    }
    __syncthreads();                 // buf0 + invn_lds ready

#pragma unroll 2
    for (int it = 0; it < 64; ++it) {
        const int cur = it & 1;
        ushort_t* base = (ushort_t*)smem + cur * 16384;

        // 1) ds_read frags from buf[cur] (conflict-free via swizzle)
        short8_t ah[4], al[4], bh[4], bl[4];
#pragma unroll
        for (int mt = 0; mt < 4; ++mt) {
            int row = wm + mt * 16 + (lane & 15);
            ah[mt] = *(const short8_t*)&base[row * 32 + kphys];
            al[mt] = *(const short8_t*)&base[4096 + row * 32 + kphys];
        }
#pragma unroll
        for (int nt = 0; nt < 4; ++nt) {
            int row = wn + nt * 16 + (lane & 15);
            bh[nt] = *(const short8_t*)&base[8192 + row * 32 + kphys];
            bl[nt] = *(const short8_t*)&base[12288 + row * 32 + kphys];
        }
        __builtin_amdgcn_sched_barrier(0);

        // 2) issue next tile's staging; stays in flight under MFMA below
        if (it + 1 < 64) STAGE(cur ^ 1, (it + 1) * 32);
        __builtin_amdgcn_sched_barrier(0);

        // 3) register-only MFMA block
#pragma unroll
        for (int mt = 0; mt < 4; ++mt)
#pragma unroll
            for (int nt = 0; nt < 4; ++nt) {
                acc[mt][nt] = __builtin_amdgcn_mfma_f32_16x16x32_bf16(ah[mt], bh[nt], acc[mt][nt], 0, 0, 0);
                acc[mt][nt] = __builtin_amdgcn_mfma_f32_16x16x32_bf16(ah[mt], bl[nt], acc[mt][nt], 0, 0, 0);
                acc[mt][nt] = __builtin_amdgcn_mfma_f32_16x16x32_bf16(al[mt], bh[nt], acc[mt][nt], 0, 0, 0);
            }
        __syncthreads();             // one barrier per K-step
    }
#undef STAGE

    // ---- CF epilogue on acc registers ----
    // C layout (16x16x32): col = lane&15, row = (lane>>4)*4 + reg.
    const float DT = T_MAX / (float)(KNOTS - 1);

#pragma unroll
    for (int nt = 0; nt < 4; ++nt) {
        const float invn = invn_lds[wn + nt * 16 + (lane & 15)];
        float re[KNOTS - 1], im[KNOTS - 1];
#pragma unroll
        for (int k = 0; k < KNOTS - 1; ++k) { re[k] = 0.f; im[k] = 0.f; }
#pragma unroll
        for (int mt = 0; mt < 4; ++mt) {
            f32x4 v = acc[mt][nt];
#pragma unroll
            for (int r = 0; r < 4; ++r) {
                float p = v[r] * invn;
                float sn, cs;
                __sincosf(p * DT, &sn, &cs);
                float c = cs, s = sn;
                re[0] += c; im[0] += s;
#pragma unroll
                for (int k = 1; k < KNOTS - 1; ++k) {
                    float cn = fmaf(c, cs, -s * sn);
                    s = fmaf(s, cs, c * sn);
                    c = cn;
                    re[k] += c; im[k] += s;
                }
            }
        }
#pragma unroll
        for (int k = 0; k < KNOTS - 1; ++k) {
            re[k] += __shfl_xor(re[k], 16);
            re[k] += __shfl_xor(re[k], 32);
            im[k] += __shfl_xor(im[k], 16);
            im[k] += __shfl_xor(im[k], 32);
        }
        if (lane < 16) {
            const int sig = nt * 16 + lane;
            float* dst = &cf[(size_t)((((wid & 1) * 2 + (wid >> 1)) * 64 + sig)) * 38];
#pragma unroll
            for (int k = 0; k < KNOTS - 1; ++k) {
                dst[2 * k]     = re[k];
                dst[2 * k + 1] = im[k];
            }
        }
    }
    __syncthreads();

    // combine the two m-parity waves; coalesced partials write
#pragma unroll
    for (int i = 0; i < KNOTS - 1; ++i) {
        const int kc2 = i * 2 + (tid >> 7);   // 0..37
        const int sl = tid & 127;
        const int g = sl >> 6, si = sl & 63;
        float v = cf[(size_t)(((0 * 2 + g) * 64 + si)) * 38 + kc2]
                + cf[(size_t)(((1 * 2 + g) * 64 + si)) * 38 + kc2];
        const int k = kc2 >> 1, c = kc2 & 1;
        partials[((size_t)(bchunk * (KNOTS - 1) + k) * 2 + c) * S_DIM + s0 + sl] = v;
    }
}

// ===========================================================================
// kfinal: sum chunk partials, weighted err, reduce, atomicAdd scalar.
// ===========================================================================
template <int NCH>
__global__ __launch_bounds__(256) void kfinal(const float* __restrict__ partials,
                                              const float* __restrict__ phi,
                                              const float* __restrict__ wts,
                                              float* __restrict__ out) {
    const int idx = blockIdx.x * 256 + threadIdx.x;
    const int kk = idx >> 11;
    const int s = idx & (S_DIM - 1);
    const float invB = 1.0f / (float)B_DIM;

    float re = 0.f, im = 0.f;
    for (int ch = 0; ch < NCH; ++ch) {
        re += partials[(size_t)((ch * (KNOTS - 1) + kk) * 2 + 0) * S_DIM + s];
        im += partials[(size_t)((ch * (KNOTS - 1) + kk) * 2 + 1) * S_DIM + s];
    }
    re = re * invB - phi[kk + 1];
    im *= invB;
    float local = wts[kk + 1] * fmaf(re, re, im * im);

    __shared__ float sred[256];
    sred[threadIdx.x] = local;
    __syncthreads();
    for (int off = 128; off > 0; off >>= 1) {
        if (threadIdx.x < off) sred[threadIdx.x] += sred[threadIdx.x + off];
        __syncthreads();
    }
    if (threadIdx.x == 0) {
        const float scale = (float)D_DIM / (float)S_DIM;
        atomicAdd(out, sred[0] * scale);
    }
}

// ===========================================================================
// Fallback fp32 path (validated round 2) for small ws_size
// ===========================================================================
#define BM 64
#define BN 64
#define BK 16
#define BTILES 2
#define NCHUNK_F (B_DIM / (BM * BTILES))

__global__ __launch_bounds__(256) void knorm(const float* __restrict__ A,
                                             float* __restrict__ norm2) {
    const int tid = threadIdx.x;
    const int j = tid & 63;
    const int g = tid >> 6;
    const int s = blockIdx.x * 64 + j;
    const int d0 = blockIdx.y * 256 + g * 64;
    float acc = 0.f;
#pragma unroll 8
    for (int i = 0; i < 64; ++i) {
        float v = A[(size_t)(d0 + i) * S_DIM + s];
        acc = fmaf(v, v, acc);
    }
    __shared__ float red[256];
    red[tid] = acc;
    __syncthreads();
    if (tid < 64) {
        float v = red[tid] + red[tid + 64] + red[tid + 128] + red[tid + 192];
        atomicAdd(&norm2[s], v);
    }
}

template <bool ATOMIC>
__global__ __launch_bounds__(256, 2) void kfused_f32(const float* __restrict__ E,
                                                     const float* __restrict__ A,
                                                     const float* __restrict__ norm2,
                                                     float* __restrict__ partials) {
    const int sblk = blockIdx.x;
    const int bchunk = blockIdx.y;
    const int s0 = sblk * BN;
    const int tid = threadIdx.x;
    const int tx = tid & 15, ty = tid >> 4;
    const int j = tid & 63, g = tid >> 6;

    __shared__ float As[BK][BM + 4];
    __shared__ float Bs[BK][BN + 4];
    __shared__ float Pj[BM][BN + 4];

    const float invn = rsqrtf(norm2[s0 + j]);
    const float DTSTEP = T_MAX / (float)(KNOTS - 1);

    float accRe[KNOTS - 1], accIm[KNOTS - 1];
#pragma unroll
    for (int k = 0; k < KNOTS - 1; ++k) { accRe[k] = 0.f; accIm[k] = 0.f; }

    const int lrow = tid >> 2, lq = tid & 3;
    const int brow = tid >> 4, bq = tid & 15;

    for (int bt = 0; bt < BTILES; ++bt) {
        const int b0 = (bchunk * BTILES + bt) * BM;
        float acc[4][4];
#pragma unroll
        for (int i = 0; i < 4; ++i)
#pragma unroll
            for (int jj = 0; jj < 4; ++jj) acc[i][jj] = 0.f;

        float4 ev = *(const float4*)&E[(size_t)(b0 + lrow) * D_DIM + 0 + lq * 4];
        float4 av = *(const float4*)&A[(size_t)(0 + brow) * S_DIM + s0 + bq * 4];

        for (int kt = 0; kt < D_DIM; kt += BK) {
            __syncthreads();
            As[lq * 4 + 0][lrow] = ev.x;
            As[lq * 4 + 1][lrow] = ev.y;
            As[lq * 4 + 2][lrow] = ev.z;
            As[lq * 4 + 3][lrow] = ev.w;
            *(float4*)&Bs[brow][bq * 4] = av;
            __syncthreads();
            if (kt + BK < D_DIM) {
                ev = *(const float4*)&E[(size_t)(b0 + lrow) * D_DIM + (kt + BK) + lq * 4];
                av = *(const float4*)&A[(size_t)(kt + BK + brow) * S_DIM + s0 + bq * 4];
            }
#pragma unroll
            for (int kk = 0; kk < BK; ++kk) {
                float4 a = *(const float4*)&As[kk][ty * 4];
                float4 b = *(const float4*)&Bs[kk][tx * 4];
                acc[0][0] = fmaf(a.x, b.x, acc[0][0]);
                acc[0][1] = fmaf(a.x, b.y, acc[0][1]);
                acc[0][2] = fmaf(a.x, b.z, acc[0][2]);
                acc[0][3] = fmaf(a.x, b.w, acc[0][3]);
                acc[1][0] = fmaf(a.y, b.x, acc[1][0]);
                acc[1][1] = fmaf(a.y, b.y, acc[1][1]);
                acc[1][2] = fmaf(a.y, b.z, acc[1][2]);
                acc[1][3] = fmaf(a.y, b.w, acc[1][3]);
                acc[2][0] = fmaf(a.z, b.x, acc[2][0]);
                acc[2][1] = fmaf(a.z, b.y, acc[2][1]);
                acc[2][2] = fmaf(a.z, b.z, acc[2][2]);
                acc[2][3] = fmaf(a.z, b.w, acc[2][3]);
                acc[3][0] = fmaf(a.w, b.x, acc[3][0]);
                acc[3][1] = fmaf(a.w, b.y, acc[3][1]);
                acc[3][2] = fmaf(a.w, b.z, acc[3][2]);
                acc[3][3] = fmaf(a.w, b.w, acc[3][3]);
            }
        }
        __syncthreads();
#pragma unroll
        for (int i = 0; i < 4; ++i)
            *(float4*)&Pj[ty * 4 + i][tx * 4] =
                make_float4(acc[i][0], acc[i][1], acc[i][2], acc[i][3]);
        __syncthreads();

#pragma unroll 2
        for (int bl = g * 16; bl < g * 16 + 16; ++bl) {
            float p = Pj[bl][j] * invn;
            float sn, cs;
            __sincosf(p * DTSTEP, &sn, &cs);
            float c = cs, s = sn;
            accRe[0] += c; accIm[0] += s;
#pragma unroll
            for (int kk = 1; kk < KNOTS - 1; ++kk) {
                float cn = fmaf(c, cs, -s * sn);
                s = fmaf(s, cs, c * sn);
                c = cn;
                accRe[kk] += c; accIm[kk] += s;
            }
        }
    }

    __syncthreads();
    float* red = &Pj[0][0];
    if (g == 0) {
#pragma unroll
        for (int kk = 0; kk < KNOTS - 1; ++kk) {
            red[(kk * 2 + 0) * 64 + j] = accRe[kk];
            red[(kk * 2 + 1) * 64 + j] = accIm[kk];
        }
    }
    __syncthreads();
    for (int gg = 1; gg < 4; ++gg) {
        if (g == gg) {
#pragma unroll
            for (int kk = 0; kk < KNOTS - 1; ++kk) {
                red[(kk * 2 + 0) * 64 + j] += accRe[kk];
                red[(kk * 2 + 1) * 64 + j] += accIm[kk];
            }
        }
        __syncthreads();
    }

    if (tid < 64) {
        for (int kk = 0; kk < KNOTS - 1; ++kk) {
            for (int c = 0; c < 2; ++c) {
                const int row = ATOMIC ? kk : (bchunk * (KNOTS - 1) + kk);
                float* dst = &partials[(size_t)(row * 2 + c) * S_DIM + s0 + tid];
                const float v = red[(kk * 2 + c) * 64 + tid];
                if (ATOMIC) atomicAdd(dst, v);
                else        *dst = v;
            }
        }
    }
}

// ===========================================================================
extern "C" void kernel_launch(void* const* d_in, const int* in_sizes, int n_in,
                              void* d_out, int out_size, void* d_ws, size_t ws_size,
                              hipStream_t stream) {
    const float* E   = (const float*)d_in[0];
    const float* A   = (const float*)d_in[1];
    const float* phi = (const float*)d_in[3];
    const float* wts = (const float*)d_in[4];
    float* out = (float*)d_out;

    float* ws_f = (float*)d_ws;

    const size_t part_elems = (size_t)32 * (KNOTS - 1) * 2 * S_DIM;  // 2,490,368
    // Big path layout: partials | norm_part | Eh | El | Aht | Alt
    float* partials = ws_f;
    float* norm_part = ws_f + part_elems;         // 32 x 2048 floats
    ushort_t* Ehp  = (ushort_t*)(norm_part + 32 * S_DIM);
    ushort_t* Elp  = Ehp + (size_t)B_DIM * D_DIM;
    ushort_t* Ahtp = Elp + (size_t)B_DIM * D_DIM;
    ushort_t* Altp = Ahtp + (size_t)S_DIM * D_DIM;

    const size_t need_bytes = (part_elems + 32 * S_DIM) * sizeof(float)
                            + (2 * (size_t)B_DIM * D_DIM + 2 * (size_t)S_DIM * D_DIM) * sizeof(ushort_t);

    if (ws_size >= need_bytes) {
        // 3 graph nodes, all well-parallelized
        kconv<<<dim3(4096 + 1024), 256, 0, stream>>>(E, A, Ehp, Elp, Ahtp, Altp, norm_part, out);
        kmain<<<dim3(S_DIM / 128, B_DIM / 128), 256, 0, stream>>>(Ehp, Elp, Ahtp, Altp, norm_part, partials);
        kfinal<32><<<dim3((KNOTS - 1) * S_DIM / 256), 256, 0, stream>>>(partials, phi, wts, out);
    } else {
        // fallback fp32 path (norm2 | partials layout)
        float* norm2 = ws_f;
        float* partials_f = ws_f + S_DIM;
        hipMemsetAsync(norm2, 0, S_DIM * sizeof(float), stream);
        hipMemsetAsync(out, 0, sizeof(float), stream);
        knorm<<<dim3(S_DIM / 64, D_DIM / 256), 256, 0, stream>>>(A, norm2);
        if (ws_size >= (S_DIM + part_elems) * sizeof(float)) {
            kfused_f32<false><<<dim3(S_DIM / BN, NCHUNK_F), 256, 0, stream>>>(E, A, norm2, partials_f);
            kfinal<NCHUNK_F><<<dim3((KNOTS - 1) * S_DIM / 256), 256, 0, stream>>>(partials_f, phi, wts, out);
        } else {
            hipMemsetAsync(partials_f, 0, (size_t)(KNOTS - 1) * 2 * S_DIM * sizeof(float), stream);
            kfused_f32<true><<<dim3(S_DIM / BN, NCHUNK_F), 256, 0, stream>>>(E, A, norm2, partials_f);
            kfinal<1><<<dim3((KNOTS - 1) * S_DIM / 256), 256, 0, stream>>>(partials_f, phi, wts, out);
        }
    }
}

// Round 7
// 178.948 us; speedup vs baseline: 2.2360x; 1.3149x over previous
//
#include <hip/hip_runtime.h>
#include <hip/hip_bf16.h>
#include <cstddef>
#include <cstdint>

// Problem constants
#define B_DIM 4096
#define D_DIM 2048
#define S_DIM 2048
#define KNOTS 20
#define T_MAX 5.0f

typedef unsigned short ushort_t;
typedef _Float16 f16_t;
typedef __attribute__((ext_vector_type(8))) _Float16 half8_t;   // 4 VGPR
typedef __attribute__((ext_vector_type(4))) _Float16 half4_t;
typedef __attribute__((ext_vector_type(4))) float f32x4;

// ---- async global->LDS 16B ----
__device__ __forceinline__ void gload16(const void* g, void* l) {
    __builtin_amdgcn_global_load_lds(
        (const __attribute__((address_space(1))) unsigned int*)g,
        (__attribute__((address_space(3))) unsigned int*)l, 16, 0, 0);
}

// ===========================================================================
// kconv: preprocessing, fully parallel.
//   blocks [0, 4096)    : E [B][D] fp32 -> Eh fp16
//   blocks [4096, 5120) : A 64x64 tile -> UNNORMALIZED Ah [S][D] fp16
//                         + per-tile column sumsq -> norm_part[dblk][s]
//   block 0 thread 0    : zeroes out[0]
// ===========================================================================
__global__ __launch_bounds__(256) void kconv(const float* __restrict__ E,
                                             const float* __restrict__ A,
                                             f16_t* __restrict__ Eh,
                                             f16_t* __restrict__ Ah,
                                             float* __restrict__ norm_part,
                                             float* __restrict__ out) {
    const int bx = blockIdx.x;
    const int tid = threadIdx.x;
    if (bx == 0 && tid == 0) out[0] = 0.f;

    if (bx < 4096) {
        const size_t i = ((size_t)bx * 256 + tid) * 8;
        float4 v0 = *(const float4*)&E[i];
        float4 v1 = *(const float4*)&E[i + 4];
        float f[8] = {v0.x, v0.y, v0.z, v0.w, v1.x, v1.y, v1.z, v1.w};
        half8_t h;
#pragma unroll
        for (int j = 0; j < 8; ++j) h[j] = (f16_t)f[j];
        *(half8_t*)&Eh[i] = h;
        return;
    }

    // ---- A tile: transpose + fp16 + partial column sumsq ----
    __shared__ float T[64][69];
    __shared__ float nr[4][64];
    const int idx = bx - 4096;                 // 0..1023
    const int dblk = idx >> 5, sblk = idx & 31;
    const int d0 = dblk * 64, s0 = sblk * 64;

    const int dl = tid >> 2, c4 = tid & 3;
#pragma unroll
    for (int q = 0; q < 4; ++q) {
        int sc = c4 * 16 + q * 4;
        float4 v = *(const float4*)&A[(size_t)(d0 + dl) * S_DIM + s0 + sc];
        T[dl][sc + 0] = v.x; T[dl][sc + 1] = v.y;
        T[dl][sc + 2] = v.z; T[dl][sc + 3] = v.w;
    }
    __syncthreads();

    {
        const int c = tid & 63, g = tid >> 6;
        float acc = 0.f;
#pragma unroll
        for (int i = 0; i < 16; ++i) {
            float v = T[g * 16 + i][c];
            acc = fmaf(v, v, acc);
        }
        nr[g][c] = acc;
    }
    __syncthreads();
    if (tid < 64)
        norm_part[(size_t)dblk * S_DIM + s0 + tid] =
            nr[0][tid] + nr[1][tid] + nr[2][tid] + nr[3][tid];

#pragma unroll
    for (int p = 0; p < 4; ++p) {
        int sl = p * 16 + (tid >> 4);
        int dof = (tid & 15) * 4;
        half4_t h;
#pragma unroll
        for (int i = 0; i < 4; ++i) h[i] = (f16_t)T[dof + i][sl];
        *(half4_t*)&Ah[(size_t)(s0 + sl) * D_DIM + d0 + dof] = h;
    }
}

// ===========================================================================
// kmain: single-term fp16 MFMA GEMM + CF epilogue.
// 128x128 tile, K_STEP=64, 4 waves, LDS dbuf 2x32KB, 2-phase pipeline:
// per K-step: ds_read(cur) -> STAGE(next) -> 32 MFMA -> barrier.
// LDS XOR swizzle: physical 16B chunk of (row r, logical chunk q) = q^(r&7);
// staging keeps LINEAR dest, pre-swizzles the GLOBAL source k-offset.
// Normalization (invn) applied in epilogue: proj*invn == (E @ A_raw)*invn.
// ===========================================================================
__global__ __launch_bounds__(256, 2) void kmain(const f16_t* __restrict__ Eh,
                                                const f16_t* __restrict__ Ah,
                                                const float* __restrict__ norm_part,
                                                float* __restrict__ partials) {
    __shared__ __align__(16) char smem[65536];   // 2 x 32KB dbuf; cf aliases
    __shared__ float invn_lds[128];
    float* cf = (float*)smem;

    const int tid = threadIdx.x;
    const int lane = tid & 63, wid = tid >> 6;
    const int wm = (wid & 1) * 64, wn = (wid >> 1) * 64;

    // T1: bijective XCD-aware remap (512 blocks, 512%8==0)
    const int lin = blockIdx.y * gridDim.x + blockIdx.x;
    const int wg = (lin & 7) * 64 + (lin >> 3);
    const int sblk = wg & 15, bchunk = wg >> 4;
    const int s0 = sblk * 128, b0 = bchunk * 128;

    f32x4 acc[4][4];
#pragma unroll
    for (int mt = 0; mt < 4; ++mt)
#pragma unroll
        for (int nt = 0; nt < 4; ++nt)
            acc[mt][nt] = (f32x4){0.f, 0.f, 0.f, 0.f};

    // staging: 4 rounds x 32 rows; row r = rnd*32 + (tid>>3), chunk (tid&7)
    const int r_st = tid >> 3;                       // row-in-round 0..31
    const int kq_src = ((tid & 7) ^ (r_st & 7)) * 8; // pre-swizzled k-offset (halves)
    const int lds_lin = tid * 8;                     // linear dest within round-block

    // frag read swizzle: phys chunk = (kc*4 + g4) ^ (fr&7)
    const int fr = lane & 15;
    const int g4 = lane >> 4;

#define STAGE(P, KT)                                                            \
    {                                                                           \
        f16_t* base_ = (f16_t*)smem + (P) * 16384;                              \
        _Pragma("unroll")                                                       \
        for (int rnd = 0; rnd < 4; ++rnd) {                                     \
            const int r_ = rnd * 32 + r_st;                                     \
            gload16(Eh + (size_t)(b0 + r_) * D_DIM + (KT) + kq_src,             \
                    base_ + rnd * 2048 + lds_lin);                              \
            gload16(Ah + (size_t)(s0 + r_) * D_DIM + (KT) + kq_src,             \
                    base_ + 8192 + rnd * 2048 + lds_lin);                       \
        }                                                                       \
    }

    STAGE(0, 0);
    // invn for this block's 128 s-columns (L2-hot; hides under STAGE(0))
    if (tid < 128) {
        float n2 = 0.f;
#pragma unroll 8
        for (int d = 0; d < 32; ++d)
            n2 += norm_part[(size_t)d * S_DIM + s0 + tid];
        invn_lds[tid] = rsqrtf(n2);
    }
    __syncthreads();                 // buf0 + invn_lds ready

#pragma unroll 2
    for (int it = 0; it < 32; ++it) {
        const int cur = it & 1;
        f16_t* base = (f16_t*)smem + cur * 16384;

        // 1) ds_read frags (conflict-free via swizzle): 16 x b128
        half8_t ae[4][2], bs[4][2];
#pragma unroll
        for (int mt = 0; mt < 4; ++mt) {
            const int row = wm + mt * 16 + fr;
#pragma unroll
            for (int kc = 0; kc < 2; ++kc) {
                const int phys = ((kc * 4 + g4) ^ (fr & 7)) * 8;
                ae[mt][kc] = *(const half8_t*)&base[row * 64 + phys];
            }
        }
#pragma unroll
        for (int nt = 0; nt < 4; ++nt) {
            const int row = wn + nt * 16 + fr;
#pragma unroll
            for (int kc = 0; kc < 2; ++kc) {
                const int phys = ((kc * 4 + g4) ^ (fr & 7)) * 8;
                bs[nt][kc] = *(const half8_t*)&base[8192 + row * 64 + phys];
            }
        }
        __builtin_amdgcn_sched_barrier(0);

        // 2) issue next tile's staging; in flight under MFMA below
        if (it + 1 < 32) STAGE(cur ^ 1, (it + 1) * 64);
        __builtin_amdgcn_sched_barrier(0);

        // 3) register-only MFMA block: 4x4 tiles x 2 k-chunks
#pragma unroll
        for (int kc = 0; kc < 2; ++kc)
#pragma unroll
            for (int mt = 0; mt < 4; ++mt)
#pragma unroll
                for (int nt = 0; nt < 4; ++nt)
                    acc[mt][nt] = __builtin_amdgcn_mfma_f32_16x16x32_f16(
                        ae[mt][kc], bs[nt][kc], acc[mt][nt], 0, 0, 0);
        __syncthreads();             // one barrier per K-step
    }
#undef STAGE

    // ---- CF epilogue on acc registers ----
    // C layout (16x16x32): col = lane&15, row = (lane>>4)*4 + reg.
    const float DT = T_MAX / (float)(KNOTS - 1);

#pragma unroll
    for (int nt = 0; nt < 4; ++nt) {
        const float invn = invn_lds[wn + nt * 16 + fr];
        float re[KNOTS - 1], im[KNOTS - 1];
#pragma unroll
        for (int k = 0; k < KNOTS - 1; ++k) { re[k] = 0.f; im[k] = 0.f; }
#pragma unroll
        for (int mt = 0; mt < 4; ++mt) {
            f32x4 v = acc[mt][nt];
#pragma unroll
            for (int r = 0; r < 4; ++r) {
                float p = v[r] * invn;
                float sn, cs;
                __sincosf(p * DT, &sn, &cs);
                float c = cs, s = sn;
                re[0] += c; im[0] += s;
#pragma unroll
                for (int k = 1; k < KNOTS - 1; ++k) {
                    float cn = fmaf(c, cs, -s * sn);
                    s = fmaf(s, cs, c * sn);
                    c = cn;
                    re[k] += c; im[k] += s;
                }
            }
        }
#pragma unroll
        for (int k = 0; k < KNOTS - 1; ++k) {
            re[k] += __shfl_xor(re[k], 16);
            re[k] += __shfl_xor(re[k], 32);
            im[k] += __shfl_xor(im[k], 16);
            im[k] += __shfl_xor(im[k], 32);
        }
        if (lane < 16) {
            const int sig = nt * 16 + lane;
            float* dst = &cf[(size_t)((((wid & 1) * 2 + (wid >> 1)) * 64 + sig)) * 38];
#pragma unroll
            for (int k = 0; k < KNOTS - 1; ++k) {
                dst[2 * k]     = re[k];
                dst[2 * k + 1] = im[k];
            }
        }
    }
    __syncthreads();

    // combine the two m-parity waves; coalesced partials write
#pragma unroll
    for (int i = 0; i < KNOTS - 1; ++i) {
        const int kc2 = i * 2 + (tid >> 7);   // 0..37
        const int sl = tid & 127;
        const int g = sl >> 6, si = sl & 63;
        float v = cf[(size_t)(((0 * 2 + g) * 64 + si)) * 38 + kc2]
                + cf[(size_t)(((1 * 2 + g) * 64 + si)) * 38 + kc2];
        const int k = kc2 >> 1, c = kc2 & 1;
        partials[((size_t)(bchunk * (KNOTS - 1) + k) * 2 + c) * S_DIM + s0 + sl] = v;
    }
}

// ===========================================================================
// kfinal: sum chunk partials, weighted err, reduce, atomicAdd scalar.
// ===========================================================================
template <int NCH>
__global__ __launch_bounds__(256) void kfinal(const float* __restrict__ partials,
                                              const float* __restrict__ phi,
                                              const float* __restrict__ wts,
                                              float* __restrict__ out) {
    const int idx = blockIdx.x * 256 + threadIdx.x;
    const int kk = idx >> 11;
    const int s = idx & (S_DIM - 1);
    const float invB = 1.0f / (float)B_DIM;

    float re = 0.f, im = 0.f;
    for (int ch = 0; ch < NCH; ++ch) {
        re += partials[(size_t)((ch * (KNOTS - 1) + kk) * 2 + 0) * S_DIM + s];
        im += partials[(size_t)((ch * (KNOTS - 1) + kk) * 2 + 1) * S_DIM + s];
    }
    re = re * invB - phi[kk + 1];
    im *= invB;
    float local = wts[kk + 1] * fmaf(re, re, im * im);

    __shared__ float sred[256];
    sred[threadIdx.x] = local;
    __syncthreads();
    for (int off = 128; off > 0; off >>= 1) {
        if (threadIdx.x < off) sred[threadIdx.x] += sred[threadIdx.x + off];
        __syncthreads();
    }
    if (threadIdx.x == 0) {
        const float scale = (float)D_DIM / (float)S_DIM;
        atomicAdd(out, sred[0] * scale);
    }
}

// ===========================================================================
// Fallback fp32 path (validated round 2) for small ws_size
// ===========================================================================
#define BM 64
#define BN 64
#define BK 16
#define BTILES 2
#define NCHUNK_F (B_DIM / (BM * BTILES))

__global__ __launch_bounds__(256) void knorm(const float* __restrict__ A,
                                             float* __restrict__ norm2) {
    const int tid = threadIdx.x;
    const int j = tid & 63;
    const int g = tid >> 6;
    const int s = blockIdx.x * 64 + j;
    const int d0 = blockIdx.y * 256 + g * 64;
    float acc = 0.f;
#pragma unroll 8
    for (int i = 0; i < 64; ++i) {
        float v = A[(size_t)(d0 + i) * S_DIM + s];
        acc = fmaf(v, v, acc);
    }
    __shared__ float red[256];
    red[tid] = acc;
    __syncthreads();
    if (tid < 64) {
        float v = red[tid] + red[tid + 64] + red[tid + 128] + red[tid + 192];
        atomicAdd(&norm2[s], v);
    }
}

template <bool ATOMIC>
__global__ __launch_bounds__(256, 2) void kfused_f32(const float* __restrict__ E,
                                                     const float* __restrict__ A,
                                                     const float* __restrict__ norm2,
                                                     float* __restrict__ partials) {
    const int sblk = blockIdx.x;
    const int bchunk = blockIdx.y;
    const int s0 = sblk * BN;
    const int tid = threadIdx.x;
    const int tx = tid & 15, ty = tid >> 4;
    const int j = tid & 63, g = tid >> 6;

    __shared__ float As[BK][BM + 4];
    __shared__ float Bs[BK][BN + 4];
    __shared__ float Pj[BM][BN + 4];

    const float invn = rsqrtf(norm2[s0 + j]);
    const float DTSTEP = T_MAX / (float)(KNOTS - 1);

    float accRe[KNOTS - 1], accIm[KNOTS - 1];
#pragma unroll
    for (int k = 0; k < KNOTS - 1; ++k) { accRe[k] = 0.f; accIm[k] = 0.f; }

    const int lrow = tid >> 2, lq = tid & 3;
    const int brow = tid >> 4, bq = tid & 15;

    for (int bt = 0; bt < BTILES; ++bt) {
        const int b0 = (bchunk * BTILES + bt) * BM;
        float acc[4][4];
#pragma unroll
        for (int i = 0; i < 4; ++i)
#pragma unroll
            for (int jj = 0; jj < 4; ++jj) acc[i][jj] = 0.f;

        float4 ev = *(const float4*)&E[(size_t)(b0 + lrow) * D_DIM + 0 + lq * 4];
        float4 av = *(const float4*)&A[(size_t)(0 + brow) * S_DIM + s0 + bq * 4];

        for (int kt = 0; kt < D_DIM; kt += BK) {
            __syncthreads();
            As[lq * 4 + 0][lrow] = ev.x;
            As[lq * 4 + 1][lrow] = ev.y;
            As[lq * 4 + 2][lrow] = ev.z;
            As[lq * 4 + 3][lrow] = ev.w;
            *(float4*)&Bs[brow][bq * 4] = av;
            __syncthreads();
            if (kt + BK < D_DIM) {
                ev = *(const float4*)&E[(size_t)(b0 + lrow) * D_DIM + (kt + BK) + lq * 4];
                av = *(const float4*)&A[(size_t)(kt + BK + brow) * S_DIM + s0 + bq * 4];
            }
#pragma unroll
            for (int kk = 0; kk < BK; ++kk) {
                float4 a = *(const float4*)&As[kk][ty * 4];
                float4 b = *(const float4*)&Bs[kk][tx * 4];
                acc[0][0] = fmaf(a.x, b.x, acc[0][0]);
                acc[0][1] = fmaf(a.x, b.y, acc[0][1]);
                acc[0][2] = fmaf(a.x, b.z, acc[0][2]);
                acc[0][3] = fmaf(a.x, b.w, acc[0][3]);
                acc[1][0] = fmaf(a.y, b.x, acc[1][0]);
                acc[1][1] = fmaf(a.y, b.y, acc[1][1]);
                acc[1][2] = fmaf(a.y, b.z, acc[1][2]);
                acc[1][3] = fmaf(a.y, b.w, acc[1][3]);
                acc[2][0] = fmaf(a.z, b.x, acc[2][0]);
                acc[2][1] = fmaf(a.z, b.y, acc[2][1]);
                acc[2][2] = fmaf(a.z, b.z, acc[2][2]);
                acc[2][3] = fmaf(a.z, b.w, acc[2][3]);
                acc[3][0] = fmaf(a.w, b.x, acc[3][0]);
                acc[3][1] = fmaf(a.w, b.y, acc[3][1]);
                acc[3][2] = fmaf(a.w, b.z, acc[3][2]);
                acc[3][3] = fmaf(a.w, b.w, acc[3][3]);
            }
        }
        __syncthreads();
#pragma unroll
        for (int i = 0; i < 4; ++i)
            *(float4*)&Pj[ty * 4 + i][tx * 4] =
                make_float4(acc[i][0], acc[i][1], acc[i][2], acc[i][3]);
        __syncthreads();

#pragma unroll 2
        for (int bl = g * 16; bl < g * 16 + 16; ++bl) {
            float p = Pj[bl][j] * invn;
            float sn, cs;
            __sincosf(p * DTSTEP, &sn, &cs);
            float c = cs, s = sn;
            accRe[0] += c; accIm[0] += s;
#pragma unroll
            for (int kk = 1; kk < KNOTS - 1; ++kk) {
                float cn = fmaf(c, cs, -s * sn);
                s = fmaf(s, cs, c * sn);
                c = cn;
                accRe[kk] += c; accIm[kk] += s;
            }
        }
    }

    __syncthreads();
    float* red = &Pj[0][0];
    if (g == 0) {
#pragma unroll
        for (int kk = 0; kk < KNOTS - 1; ++kk) {
            red[(kk * 2 + 0) * 64 + j] = accRe[kk];
            red[(kk * 2 + 1) * 64 + j] = accIm[kk];
        }
    }
    __syncthreads();
    for (int gg = 1; gg < 4; ++gg) {
        if (g == gg) {
#pragma unroll
            for (int kk = 0; kk < KNOTS - 1; ++kk) {
                red[(kk * 2 + 0) * 64 + j] += accRe[kk];
                red[(kk * 2 + 1) * 64 + j] += accIm[kk];
            }
        }
        __syncthreads();
    }

    if (tid < 64) {
        for (int kk = 0; kk < KNOTS - 1; ++kk) {
            for (int c = 0; c < 2; ++c) {
                const int row = ATOMIC ? kk : (bchunk * (KNOTS - 1) + kk);
                float* dst = &partials[(size_t)(row * 2 + c) * S_DIM + s0 + tid];
                const float v = red[(kk * 2 + c) * 64 + tid];
                if (ATOMIC) atomicAdd(dst, v);
                else        *dst = v;
            }
        }
    }
}

// ===========================================================================
extern "C" void kernel_launch(void* const* d_in, const int* in_sizes, int n_in,
                              void* d_out, int out_size, void* d_ws, size_t ws_size,
                              hipStream_t stream) {
    const float* E   = (const float*)d_in[0];
    const float* A   = (const float*)d_in[1];
    const float* phi = (const float*)d_in[3];
    const float* wts = (const float*)d_in[4];
    float* out = (float*)d_out;

    float* ws_f = (float*)d_ws;

    const size_t part_elems = (size_t)32 * (KNOTS - 1) * 2 * S_DIM;  // 2,490,368
    // Big path layout: partials | norm_part | Eh (f16) | Ah (f16)
    float* partials = ws_f;
    float* norm_part = ws_f + part_elems;         // 32 x 2048 floats
    f16_t* Ehp = (f16_t*)(norm_part + 32 * S_DIM);
    f16_t* Ahp = Ehp + (size_t)B_DIM * D_DIM;

    const size_t need_bytes = (part_elems + 32 * S_DIM) * sizeof(float)
                            + ((size_t)B_DIM * D_DIM + (size_t)S_DIM * D_DIM) * sizeof(f16_t);

    if (ws_size >= need_bytes) {
        // 3 graph nodes, all well-parallelized
        kconv<<<dim3(4096 + 1024), 256, 0, stream>>>(E, A, Ehp, Ahp, norm_part, out);
        kmain<<<dim3(S_DIM / 128, B_DIM / 128), 256, 0, stream>>>(Ehp, Ahp, norm_part, partials);
        kfinal<32><<<dim3((KNOTS - 1) * S_DIM / 256), 256, 0, stream>>>(partials, phi, wts, out);
    } else {
        // fallback fp32 path (norm2 | partials layout)
        float* norm2 = ws_f;
        float* partials_f = ws_f + S_DIM;
        hipMemsetAsync(norm2, 0, S_DIM * sizeof(float), stream);
        hipMemsetAsync(out, 0, sizeof(float), stream);
        knorm<<<dim3(S_DIM / 64, D_DIM / 256), 256, 0, stream>>>(A, norm2);
        if (ws_size >= (S_DIM + part_elems) * sizeof(float)) {
            kfused_f32<false><<<dim3(S_DIM / BN, NCHUNK_F), 256, 0, stream>>>(E, A, norm2, partials_f);
            kfinal<NCHUNK_F><<<dim3((KNOTS - 1) * S_DIM / 256), 256, 0, stream>>>(partials_f, phi, wts, out);
        } else {
            hipMemsetAsync(partials_f, 0, (size_t)(KNOTS - 1) * 2 * S_DIM * sizeof(float), stream);
            kfused_f32<true><<<dim3(S_DIM / BN, NCHUNK_F), 256, 0, stream>>>(E, A, norm2, partials_f);
            kfinal<1><<<dim3((KNOTS - 1) * S_DIM / 256), 256, 0, stream>>>(partials_f, phi, wts, out);
        }
    }
}